// Round 1
// baseline (611.650 us; speedup 1.0000x reference)
//
#include <hip/hip_runtime.h>

#define N_NODES 50000
#define N_EDGES 800000
#define D 128

// --- kernel 1: in/out degree counts over the 800K edges ---
__global__ void k_degrees(const int* __restrict__ el,
                          int* __restrict__ deg_in, int* __restrict__ deg_out) {
    int e = blockIdx.x * blockDim.x + threadIdx.x;
    if (e < N_EDGES) {
        int s = el[2 * e];
        int t = el[2 * e + 1];
        atomicAdd(&deg_in[s], 1);
        atomicAdd(&deg_out[t], 1);
    }
}

// --- kernel 2: update[n] = x[n] * w_self(n)  (the appended self-loops) ---
__global__ void k_init(const float4* __restrict__ x4,
                       const int* __restrict__ deg_in, const int* __restrict__ deg_out,
                       float4* __restrict__ upd4) {
    int gid = blockIdx.x * blockDim.x + threadIdx.x;  // N*32 float4 groups
    if (gid >= N_NODES * 32) return;
    int n = gid >> 5;
    float din  = (float)(deg_in[n]  + 1);
    float dout = (float)(deg_out[n] + 1);
    float w = 1.0f / (sqrtf(din * dout) + 1e-10f);
    float4 v = x4[gid];
    v.x *= w; v.y *= w; v.z *= w; v.w *= w;
    upd4[gid] = v;
}

// --- kernel 3: edge scatter: update[t] += w(s,t) * x[s] ---
// one thread per (edge, feature); 128 consecutive threads share an edge
// -> coalesced 512B gather of x[s], coalesced contiguous atomics on update[t]
__global__ void k_scatter(const int* __restrict__ el, const float* __restrict__ x,
                          const int* __restrict__ deg_in, const int* __restrict__ deg_out,
                          float* __restrict__ upd) {
    int gid = blockIdx.x * blockDim.x + threadIdx.x;  // E*128 = 102.4M < 2^31
    int e = gid >> 7;
    int d = gid & 127;
    int s = el[2 * e];
    int t = el[2 * e + 1];
    float din  = (float)(deg_in[s]  + 1);
    float dout = (float)(deg_out[t] + 1);
    float w = 1.0f / (sqrtf(din * dout) + 1e-10f);
    atomicAdd(&upd[t * D + d], w * x[s * D + d]);
}

// --- kernel 4: out[n] = relu(update[n] @ W^T + b), in-place on d_out ---
// block = 256 threads, 64 nodes/block. u staged in LDS (stride 132: float4-aligned,
// breaks 32-bank aliasing). W read as float4 from global (64KB, L2-resident).
// Register tile: 4 nodes x 8 outputs per thread -> 4096 FMAs/thread.
__global__ __launch_bounds__(256) void k_gemm(const float* __restrict__ W,
                                              const float* __restrict__ b,
                                              float* __restrict__ out) {
    __shared__ float uS[64 * 132];
    const int base = blockIdx.x * 64;
    const int tid = threadIdx.x;

    // stage 64 rows of update (= current d_out contents) into LDS
    for (int i = tid; i < 64 * 32; i += 256) {
        int n = i >> 5, c = i & 31;
        int node = base + n;
        float4 v = make_float4(0.f, 0.f, 0.f, 0.f);
        if (node < N_NODES) v = *(const float4*)&out[node * D + c * 4];
        *(float4*)&uS[n * 132 + c * 4] = v;
    }
    __syncthreads();

    const int tx = tid & 15;   // output group: j = tx + 16*jj
    const int ty = tid >> 4;   // node group:   n = base + ty*4 + mm

    float acc[4][8];
    for (int jj = 0; jj < 8; ++jj) {
        float bj = b[tx + 16 * jj];
        for (int mm = 0; mm < 4; ++mm) acc[mm][jj] = bj;
    }

    for (int c4 = 0; c4 < 32; ++c4) {
        float4 uk[4];
        #pragma unroll
        for (int mm = 0; mm < 4; ++mm)
            uk[mm] = *(const float4*)&uS[(ty * 4 + mm) * 132 + c4 * 4];
        #pragma unroll
        for (int jj = 0; jj < 8; ++jj) {
            int j = tx + 16 * jj;
            float4 w = *(const float4*)&W[j * D + c4 * 4];
            #pragma unroll
            for (int mm = 0; mm < 4; ++mm) {
                acc[mm][jj] += uk[mm].x * w.x + uk[mm].y * w.y
                             + uk[mm].z * w.z + uk[mm].w * w.w;
            }
        }
    }

    // epilogue: bias already folded in; relu + store (overwrites staged rows)
    for (int mm = 0; mm < 4; ++mm) {
        int node = base + ty * 4 + mm;
        if (node < N_NODES) {
            #pragma unroll
            for (int jj = 0; jj < 8; ++jj) {
                float v = acc[mm][jj];
                out[node * D + tx + 16 * jj] = v > 0.0f ? v : 0.0f;
            }
        }
    }
}

extern "C" void kernel_launch(void* const* d_in, const int* in_sizes, int n_in,
                              void* d_out, int out_size, void* d_ws, size_t ws_size,
                              hipStream_t stream) {
    const int*   el = (const int*)d_in[0];    // [E,2] int32
    const float* x  = (const float*)d_in[1];  // [N,128] f32
    const float* W  = (const float*)d_in[2];  // [128,128] f32
    const float* b  = (const float*)d_in[3];  // [128] f32
    float* out = (float*)d_out;               // [N,128] f32; also holds `update`

    int* deg_in  = (int*)d_ws;                // N ints
    int* deg_out = deg_in + N_NODES;          // N ints

    hipMemsetAsync(d_ws, 0, 2 * N_NODES * sizeof(int), stream);

    k_degrees<<<(N_EDGES + 255) / 256, 256, 0, stream>>>(el, deg_in, deg_out);

    k_init<<<(N_NODES * 32 + 255) / 256, 256, 0, stream>>>(
        (const float4*)x, deg_in, deg_out, (float4*)out);

    k_scatter<<<(N_EDGES * 128) / 256, 256, 0, stream>>>(
        el, x, deg_in, deg_out, out);

    k_gemm<<<(N_NODES + 63) / 64, 256, 0, stream>>>(W, b, out);
}

// Round 2
// 335.528 us; speedup vs baseline: 1.8229x; 1.8229x over previous
//
#include <hip/hip_runtime.h>

#define N_NODES 50000
#define N_EDGES 800000
#define D 128
#define NBLK 196  // ceil(50000/256)

// ---------------- CSR-build pipeline ----------------

// degrees over the 800K edges (int atomics on 200KB tables — cheap)
__global__ void k_degrees(const int* __restrict__ el,
                          int* __restrict__ deg_in, int* __restrict__ deg_out) {
    int e = blockIdx.x * blockDim.x + threadIdx.x;
    if (e < N_EDGES) {
        atomicAdd(&deg_in[el[2 * e]], 1);
        atomicAdd(&deg_out[el[2 * e + 1]], 1);
    }
}

// rs[n] = rsqrt(deg_in[n]+1), rd[n] = rsqrt(deg_out[n]+1)
// (eps=1e-10 in ref is negligible: sqrt(din*dout) >= 1)
__global__ void k_rsq(const int* __restrict__ deg_in, const int* __restrict__ deg_out,
                      float* __restrict__ rs, float* __restrict__ rd) {
    int n = blockIdx.x * blockDim.x + threadIdx.x;
    if (n < N_NODES) {
        rs[n] = rsqrtf((float)(deg_in[n] + 1));
        rd[n] = rsqrtf((float)(deg_out[n] + 1));
    }
}

// scan stage a: per-block sums of deg_out
__global__ void k_scan_a(const int* __restrict__ deg_out, int* __restrict__ blk_sum) {
    __shared__ int sc[256];
    int t = threadIdx.x;
    int g = blockIdx.x * 256 + t;
    sc[t] = (g < N_NODES) ? deg_out[g] : 0;
    __syncthreads();
    for (int s = 128; s > 0; s >>= 1) {
        if (t < s) sc[t] += sc[t + s];
        __syncthreads();
    }
    if (t == 0) blk_sum[blockIdx.x] = sc[0];
}

// scan stage b: exclusive scan of the NBLK block sums (single block)
__global__ void k_scan_b(const int* __restrict__ blk_sum, int* __restrict__ blk_off) {
    __shared__ int sc[256];
    int t = threadIdx.x;
    int v = (t < NBLK) ? blk_sum[t] : 0;
    sc[t] = v;
    __syncthreads();
    for (int off = 1; off < 256; off <<= 1) {
        int a = (t >= off) ? sc[t - off] : 0;
        __syncthreads();
        sc[t] += a;
        __syncthreads();
    }
    if (t < NBLK) blk_off[t] = sc[t] - v;  // exclusive
}

// scan stage c: row_start[g] = blk_off[blk] + exclusive-in-block scan
__global__ void k_scan_c(const int* __restrict__ deg_out, const int* __restrict__ blk_off,
                         int* __restrict__ row_start) {
    __shared__ int sc[256];
    int t = threadIdx.x;
    int g = blockIdx.x * 256 + t;
    int v = (g < N_NODES) ? deg_out[g] : 0;
    sc[t] = v;
    __syncthreads();
    for (int off = 1; off < 256; off <<= 1) {
        int a = (t >= off) ? sc[t - off] : 0;
        __syncthreads();
        sc[t] += a;
        __syncthreads();
    }
    if (g < N_NODES) row_start[g] = blk_off[blockIdx.x] + sc[t] - v;
}

// counting-sort placement: bucket edges by destination; store (src, weight)
__global__ void k_fill(const int* __restrict__ el, const int* __restrict__ row_start,
                       int* __restrict__ cursor, const float* __restrict__ rs,
                       const float* __restrict__ rd, float2* __restrict__ srcw) {
    int e = blockIdx.x * blockDim.x + threadIdx.x;
    if (e < N_EDGES) {
        int s = el[2 * e];
        int t = el[2 * e + 1];
        int pos = row_start[t] + atomicAdd(&cursor[t], 1);
        srcw[pos] = make_float2(__int_as_float(s), rs[s] * rd[t]);
    }
}

// ---------------- gather (atomic-free aggregation) ----------------
// 128 threads per destination node (2 nodes / 256-block); edge loop unrolled x4
// so 4 gathers of x[s] are in flight -> hides L2/L3 latency.
__global__ __launch_bounds__(256) void k_gather(const float* __restrict__ x,
                                                const float2* __restrict__ srcw,
                                                const int* __restrict__ row_start,
                                                const int* __restrict__ deg_out,
                                                const float* __restrict__ rs,
                                                const float* __restrict__ rd,
                                                float* __restrict__ upd) {
    int n = blockIdx.x * 2 + (threadIdx.x >> 7);  // grid 25000, N=50000 exact
    int d = threadIdx.x & 127;
    int cnt = deg_out[n];
    const float2* p = srcw + row_start[n];
    float acc = rs[n] * rd[n] * x[n * D + d];  // self-loop term
    int k = 0;
    for (; k + 4 <= cnt; k += 4) {
        float2 e0 = p[k], e1 = p[k + 1], e2 = p[k + 2], e3 = p[k + 3];
        int s0 = __float_as_int(e0.x), s1 = __float_as_int(e1.x);
        int s2 = __float_as_int(e2.x), s3 = __float_as_int(e3.x);
        float v0 = x[s0 * D + d], v1 = x[s1 * D + d];
        float v2 = x[s2 * D + d], v3 = x[s3 * D + d];
        acc += e0.y * v0;
        acc += e1.y * v1;
        acc += e2.y * v2;
        acc += e3.y * v3;
    }
    for (; k < cnt; ++k) {
        float2 e = p[k];
        acc += e.y * x[__float_as_int(e.x) * D + d];
    }
    upd[n * D + d] = acc;
}

// ---------------- combine: out = relu(u @ W^T + b), in place ----------------
// W staged in LDS (row stride 132 floats: 16B-aligned, 2-way bank alias = free).
// u rows read straight from global (L2) with lane-broadcast.
__global__ __launch_bounds__(256) void k_gemm(const float* __restrict__ W,
                                              const float* __restrict__ b,
                                              float* __restrict__ out) {
    __shared__ float Wl[128 * 132];
    const int base = blockIdx.x * 64;
    const int tid = threadIdx.x;

    for (int i = tid; i < 128 * 32; i += 256) {
        int r = i >> 5, c = i & 31;
        *(float4*)&Wl[r * 132 + c * 4] = *(const float4*)&W[r * D + c * 4];
    }
    __syncthreads();

    const int tx = tid & 15;   // output j = tx + 16*jj
    const int ty = tid >> 4;   // node n = base + ty*4 + mm

    float acc[4][8];
    for (int jj = 0; jj < 8; ++jj) {
        float bj = b[tx + 16 * jj];
        for (int mm = 0; mm < 4; ++mm) acc[mm][jj] = bj;
    }

    for (int c4 = 0; c4 < 32; ++c4) {
        float4 uk[4];
        #pragma unroll
        for (int mm = 0; mm < 4; ++mm) {
            int node = base + ty * 4 + mm;
            uk[mm] = (node < N_NODES) ? *(const float4*)&out[node * D + c4 * 4]
                                      : make_float4(0.f, 0.f, 0.f, 0.f);
        }
        #pragma unroll
        for (int jj = 0; jj < 8; ++jj) {
            float4 w = *(const float4*)&Wl[(tx + 16 * jj) * 132 + c4 * 4];
            #pragma unroll
            for (int mm = 0; mm < 4; ++mm) {
                acc[mm][jj] += uk[mm].x * w.x + uk[mm].y * w.y
                             + uk[mm].z * w.z + uk[mm].w * w.w;
            }
        }
    }

    for (int mm = 0; mm < 4; ++mm) {
        int node = base + ty * 4 + mm;
        if (node < N_NODES) {
            #pragma unroll
            for (int jj = 0; jj < 8; ++jj) {
                float v = acc[mm][jj];
                out[node * D + tx + 16 * jj] = v > 0.0f ? v : 0.0f;
            }
        }
    }
}

extern "C" void kernel_launch(void* const* d_in, const int* in_sizes, int n_in,
                              void* d_out, int out_size, void* d_ws, size_t ws_size,
                              hipStream_t stream) {
    const int*   el = (const int*)d_in[0];
    const float* x  = (const float*)d_in[1];
    const float* W  = (const float*)d_in[2];
    const float* b  = (const float*)d_in[3];
    float* out = (float*)d_out;  // holds `update` between gather and gemm

    // workspace layout (4B units)
    int*    deg_in    = (int*)d_ws;                 // N
    int*    deg_out   = deg_in + N_NODES;           // N
    int*    cursor    = deg_in + 2 * N_NODES;       // N
    float*  rs        = (float*)(deg_in + 3 * N_NODES);  // N
    float*  rd        = rs + N_NODES;               // N
    int*    row_start = (int*)(rd + N_NODES);       // N
    int*    blk_sum   = row_start + N_NODES;        // 256
    int*    blk_off   = blk_sum + 256;              // 256
    float2* srcw      = (float2*)(blk_off + 256);   // E float2 (8B-aligned: 6N+512 even)

    hipMemsetAsync(d_ws, 0, 3 * N_NODES * sizeof(int), stream);

    k_degrees<<<(N_EDGES + 255) / 256, 256, 0, stream>>>(el, deg_in, deg_out);
    k_rsq<<<NBLK, 256, 0, stream>>>(deg_in, deg_out, rs, rd);
    k_scan_a<<<NBLK, 256, 0, stream>>>(deg_out, blk_sum);
    k_scan_b<<<1, 256, 0, stream>>>(blk_sum, blk_off);
    k_scan_c<<<NBLK, 256, 0, stream>>>(deg_out, blk_off, row_start);
    k_fill<<<(N_EDGES + 255) / 256, 256, 0, stream>>>(el, row_start, cursor, rs, rd, srcw);
    k_gather<<<N_NODES / 2, 256, 0, stream>>>(x, srcw, row_start, deg_out, rs, rd, out);
    k_gemm<<<(N_NODES + 63) / 64, 256, 0, stream>>>(W, b, out);
}

// Round 3
// 263.867 us; speedup vs baseline: 2.3180x; 1.2716x over previous
//
#include <hip/hip_runtime.h>

#define N_NODES 50000
#define N_EDGES 800000
#define D 128
#define NBLK 196  // ceil(50000/256)

typedef __attribute__((ext_vector_type(8))) short short8;   // 8 bf16 = 4 VGPRs
typedef __attribute__((ext_vector_type(4))) float f32x4;    // MFMA acc

__device__ __forceinline__ unsigned short f2bf(float f) {
    unsigned u = __float_as_uint(f);
    return (unsigned short)((u + 0x7FFFu + ((u >> 16) & 1u)) >> 16);  // RNE
}

// ---------------- CSR-build pipeline ----------------

__global__ void k_degrees(const int2* __restrict__ el2,
                          int* __restrict__ deg_in, int* __restrict__ deg_out) {
    int e = blockIdx.x * blockDim.x + threadIdx.x;
    if (e < N_EDGES) {
        int2 st = el2[e];
        atomicAdd(&deg_in[st.x], 1);
        atomicAdd(&deg_out[st.y], 1);
    }
}

__global__ void k_scan_a(const int* __restrict__ deg_out, int* __restrict__ blk_sum) {
    __shared__ int sc[256];
    int t = threadIdx.x;
    int g = blockIdx.x * 256 + t;
    sc[t] = (g < N_NODES) ? deg_out[g] : 0;
    __syncthreads();
    for (int s = 128; s > 0; s >>= 1) {
        if (t < s) sc[t] += sc[t + s];
        __syncthreads();
    }
    if (t == 0) blk_sum[blockIdx.x] = sc[0];
}

__global__ void k_scan_b(const int* __restrict__ blk_sum, int* __restrict__ blk_off) {
    __shared__ int sc[256];
    int t = threadIdx.x;
    int v = (t < NBLK) ? blk_sum[t] : 0;
    sc[t] = v;
    __syncthreads();
    for (int off = 1; off < 256; off <<= 1) {
        int a = (t >= off) ? sc[t - off] : 0;
        __syncthreads();
        sc[t] += a;
        __syncthreads();
    }
    if (t < NBLK) blk_off[t] = sc[t] - v;  // exclusive
}

// row_start + cursor (cursor = mutable copy consumed by k_fill)
__global__ void k_scan_c(const int* __restrict__ deg_out, const int* __restrict__ blk_off,
                         int* __restrict__ row_start, int* __restrict__ cursor) {
    __shared__ int sc[256];
    int t = threadIdx.x;
    int g = blockIdx.x * 256 + t;
    int v = (g < N_NODES) ? deg_out[g] : 0;
    sc[t] = v;
    __syncthreads();
    for (int off = 1; off < 256; off <<= 1) {
        int a = (t >= off) ? sc[t - off] : 0;
        __syncthreads();
        sc[t] += a;
        __syncthreads();
    }
    if (g < N_NODES) {
        int rs = blk_off[blockIdx.x] + sc[t] - v;
        row_start[g] = rs;
        cursor[g] = rs;
    }
}

// bucket edges by destination; weight computed inline (eps=1e-10 negligible)
__global__ void k_fill(const int2* __restrict__ el2, int* __restrict__ cursor,
                       const int* __restrict__ deg_in, const int* __restrict__ deg_out,
                       float2* __restrict__ srcw) {
    int e = blockIdx.x * blockDim.x + threadIdx.x;
    if (e < N_EDGES) {
        int2 st = el2[e];
        float w = rsqrtf((float)(deg_in[st.x] + 1) * (float)(deg_out[st.y] + 1));
        int pos = atomicAdd(&cursor[st.y], 1);
        srcw[pos] = make_float2(__int_as_float(st.x), w);
    }
}

// ---------------- gather: update[n] = sum_{(s,n)} w * x[s] + w_self * x[n] ----------------
// 32 lanes per node (float4/lane), edge loop unrolled x4 -> 4 float4 gathers in flight.
__global__ __launch_bounds__(256) void k_gather(const float4* __restrict__ x4,
                                                const float2* __restrict__ srcw,
                                                const int* __restrict__ row_start,
                                                const int* __restrict__ deg_in,
                                                const int* __restrict__ deg_out,
                                                float4* __restrict__ upd4) {
    int n  = blockIdx.x * 8 + (threadIdx.x >> 5);  // grid 6250*8 = 50000 exact
    int d4 = threadIdx.x & 31;
    int cnt = deg_out[n];
    float wself = rsqrtf((float)(deg_in[n] + 1) * (float)(cnt + 1));
    float4 v = x4[n * 32 + d4];
    float4 acc = make_float4(wself * v.x, wself * v.y, wself * v.z, wself * v.w);
    const float2* p = srcw + row_start[n];
    int k = 0;
    for (; k + 4 <= cnt; k += 4) {
        float2 e0 = p[k], e1 = p[k + 1], e2 = p[k + 2], e3 = p[k + 3];
        float4 v0 = x4[__float_as_int(e0.x) * 32 + d4];
        float4 v1 = x4[__float_as_int(e1.x) * 32 + d4];
        float4 v2 = x4[__float_as_int(e2.x) * 32 + d4];
        float4 v3 = x4[__float_as_int(e3.x) * 32 + d4];
        acc.x += e0.y * v0.x; acc.y += e0.y * v0.y; acc.z += e0.y * v0.z; acc.w += e0.y * v0.w;
        acc.x += e1.y * v1.x; acc.y += e1.y * v1.y; acc.z += e1.y * v1.z; acc.w += e1.y * v1.w;
        acc.x += e2.y * v2.x; acc.y += e2.y * v2.y; acc.z += e2.y * v2.z; acc.w += e2.y * v2.w;
        acc.x += e3.y * v3.x; acc.y += e3.y * v3.y; acc.z += e3.y * v3.z; acc.w += e3.y * v3.w;
    }
    for (; k < cnt; ++k) {
        float2 e = p[k];
        float4 vv = x4[__float_as_int(e.x) * 32 + d4];
        acc.x += e.y * vv.x; acc.y += e.y * vv.y; acc.z += e.y * vv.z; acc.w += e.y * vv.w;
    }
    upd4[n * 32 + d4] = acc;
}

// ---------------- combine: out = relu(u @ W^T + b) via bf16 MFMA, in place ----------------
// W: f32 -> bf16 staged in LDS (stride 136 bf16: 16B-aligned rows, 2-way bank alias = free).
// Each wave handles 16 nodes; reads ONLY those 16 rows of u (f32, in d_out), converts to
// bf16 A-frags in-register, MFMAs against LDS W, writes the same 16 rows -> in-place safe.
// A layout: A[m=lane&15][k=quad*8+j]; B[k=quad*8+j][n=lane&15] (= W[lane&15 + 16jj][k]);
// C/D: col=lane&15, row=quad*4+reg  (m89/m91-verified).
__global__ __launch_bounds__(256) void k_gemm(const float* __restrict__ W,
                                              const float* __restrict__ b,
                                              float* __restrict__ out) {
    __shared__ unsigned short Wl[128 * 136];
    const int tid = threadIdx.x;
    const int base = blockIdx.x * 64;

    for (int i = tid; i < 128 * 32; i += 256) {
        int r = i >> 5, c = i & 31;
        float4 w4 = *(const float4*)&W[r * D + c * 4];
        ushort4 h;
        h.x = f2bf(w4.x); h.y = f2bf(w4.y); h.z = f2bf(w4.z); h.w = f2bf(w4.w);
        *(ushort4*)&Wl[r * 136 + c * 4] = h;
    }
    __syncthreads();

    const int wv = tid >> 6;
    const int lane = tid & 63;
    const int ml = lane & 15;
    const int q = lane >> 4;

    const int arow = base + wv * 16 + ml;
    const bool rowok = arow < N_NODES;

    short8 a[4];
    #pragma unroll
    for (int kt = 0; kt < 4; ++kt) {
        float4 u0 = make_float4(0.f, 0.f, 0.f, 0.f);
        float4 u1 = u0;
        if (rowok) {
            u0 = *(const float4*)&out[arow * D + kt * 32 + q * 8];
            u1 = *(const float4*)&out[arow * D + kt * 32 + q * 8 + 4];
        }
        short8 t;
        t[0] = (short)f2bf(u0.x); t[1] = (short)f2bf(u0.y);
        t[2] = (short)f2bf(u0.z); t[3] = (short)f2bf(u0.w);
        t[4] = (short)f2bf(u1.x); t[5] = (short)f2bf(u1.y);
        t[6] = (short)f2bf(u1.z); t[7] = (short)f2bf(u1.w);
        a[kt] = t;
    }

    f32x4 acc[8];
    #pragma unroll
    for (int jj = 0; jj < 8; ++jj) acc[jj] = (f32x4){0.f, 0.f, 0.f, 0.f};

    #pragma unroll
    for (int jj = 0; jj < 8; ++jj) {
        #pragma unroll
        for (int kt = 0; kt < 4; ++kt) {
            short8 bw = *(const short8*)&Wl[(jj * 16 + ml) * 136 + kt * 32 + q * 8];
            acc[jj] = __builtin_amdgcn_mfma_f32_16x16x32_bf16(a[kt], bw, acc[jj], 0, 0, 0);
        }
    }

    #pragma unroll
    for (int jj = 0; jj < 8; ++jj) {
        float bj = b[jj * 16 + ml];
        #pragma unroll
        for (int r4 = 0; r4 < 4; ++r4) {
            int node = base + wv * 16 + q * 4 + r4;
            if (node < N_NODES) {
                float v = acc[jj][r4] + bj;
                out[node * D + jj * 16 + ml] = v > 0.f ? v : 0.f;
            }
        }
    }
}

extern "C" void kernel_launch(void* const* d_in, const int* in_sizes, int n_in,
                              void* d_out, int out_size, void* d_ws, size_t ws_size,
                              hipStream_t stream) {
    const int*   el = (const int*)d_in[0];
    const float* x  = (const float*)d_in[1];
    const float* W  = (const float*)d_in[2];
    const float* b  = (const float*)d_in[3];
    float* out = (float*)d_out;  // holds `update` (f32) between gather and gemm

    int*    deg_in    = (int*)d_ws;                  // N
    int*    deg_out   = deg_in + N_NODES;            // N
    int*    cursor    = deg_in + 2 * N_NODES;        // N
    int*    row_start = deg_in + 3 * N_NODES;        // N
    int*    blk_sum   = deg_in + 4 * N_NODES;        // 256
    int*    blk_off   = blk_sum + 256;               // 256
    float2* srcw      = (float2*)(blk_off + 256);    // E float2 (16B-aligned offset)

    hipMemsetAsync(d_ws, 0, 2 * N_NODES * sizeof(int), stream);

    k_degrees<<<N_EDGES / 256, 256, 0, stream>>>((const int2*)el, deg_in, deg_out);
    k_scan_a<<<NBLK, 256, 0, stream>>>(deg_out, blk_sum);
    k_scan_b<<<1, 256, 0, stream>>>(blk_sum, blk_off);
    k_scan_c<<<NBLK, 256, 0, stream>>>(deg_out, blk_off, row_start, cursor);
    k_fill<<<N_EDGES / 256, 256, 0, stream>>>((const int2*)el, cursor, deg_in, deg_out, srcw);
    k_gather<<<N_NODES / 8, 256, 0, stream>>>((const float4*)x, srcw, row_start,
                                              deg_in, deg_out, (float4*)out);
    k_gemm<<<(N_NODES + 63) / 64, 256, 0, stream>>>(W, b, out);
}

// Round 4
// 204.062 us; speedup vs baseline: 2.9974x; 1.2931x over previous
//
#include <hip/hip_runtime.h>

#define N_NODES 50000
#define N_EDGES 800000
#define D 128
#define NBLK 196            // ceil(50000/256) for scans
#define HP 128              // histogram partial blocks
#define EPB (N_EDGES / HP)  // 6250 edges per hist block
#define NW (N_NODES / 2)    // 25000 packed u32 words (2 nodes/word)

typedef __attribute__((ext_vector_type(8))) short short8;   // 8 bf16
typedef __attribute__((ext_vector_type(4))) float f32x4;

__device__ __forceinline__ unsigned short f2bf(float f) {
    unsigned u = __float_as_uint(f);
    return (unsigned short)((u + 0x7FFFu + ((u >> 16) & 1u)) >> 16);  // RNE
}
__device__ __forceinline__ float bf2f(unsigned short h) {
    return __uint_as_float((unsigned)h << 16);
}

// ---- degrees via per-block LDS histograms (no global atomics) ----
// LDS word w packs: in[2w](b0) | out[2w](b1) | in[2w+1](b2) | out[2w+1](b3), u8 each.
// Per-block per-node count <= 6250 random edges / 50K nodes -> u8 never overflows.
__global__ __launch_bounds__(256) void k_hist(const int2* __restrict__ el2,
                                              unsigned int* __restrict__ partials) {
    __shared__ unsigned int h[NW];  // 100 KB
    int t = threadIdx.x;
    for (int i = t; i < NW / 4; i += 256) ((uint4*)h)[i] = make_uint4(0, 0, 0, 0);
    __syncthreads();
    const int2* p = el2 + blockIdx.x * EPB;
    for (int i = t; i < EPB; i += 256) {
        int2 st = p[i];
        atomicAdd(&h[st.x >> 1], 1u << ((st.x & 1) * 16));       // in-degree byte
        atomicAdd(&h[st.y >> 1], 256u << ((st.y & 1) * 16));     // out-degree byte
    }
    __syncthreads();
    uint4* dst = (uint4*)(partials + (size_t)blockIdx.x * NW);
    for (int i = t; i < NW / 4; i += 256) dst[i] = ((uint4*)h)[i];
}

// sum the HP partials with packed-u16 masked adds (128*255 < 65536: no carry)
__global__ void k_reduce(const unsigned int* __restrict__ partials,
                         int* __restrict__ deg_in, int* __restrict__ deg_out) {
    int w = blockIdx.x * blockDim.x + threadIdx.x;
    if (w >= NW) return;
    unsigned int si = 0, so = 0;
    for (int p = 0; p < HP; ++p) {
        unsigned int v = partials[p * NW + w];
        si += v & 0x00FF00FFu;
        so += (v >> 8) & 0x00FF00FFu;
    }
    *(int2*)&deg_in[2 * w]  = make_int2(si & 0xFFFF, si >> 16);
    *(int2*)&deg_out[2 * w] = make_int2(so & 0xFFFF, so >> 16);
}

// ---- scans over deg_out -> row_start (+ cursor copy for k_fill) ----
__global__ void k_scan_a(const int* __restrict__ deg_out, int* __restrict__ blk_sum) {
    __shared__ int sc[256];
    int t = threadIdx.x;
    int g = blockIdx.x * 256 + t;
    sc[t] = (g < N_NODES) ? deg_out[g] : 0;
    __syncthreads();
    for (int s = 128; s > 0; s >>= 1) {
        if (t < s) sc[t] += sc[t + s];
        __syncthreads();
    }
    if (t == 0) blk_sum[blockIdx.x] = sc[0];
}

__global__ void k_scan_b(const int* __restrict__ blk_sum, int* __restrict__ blk_off) {
    __shared__ int sc[256];
    int t = threadIdx.x;
    int v = (t < NBLK) ? blk_sum[t] : 0;
    sc[t] = v;
    __syncthreads();
    for (int off = 1; off < 256; off <<= 1) {
        int a = (t >= off) ? sc[t - off] : 0;
        __syncthreads();
        sc[t] += a;
        __syncthreads();
    }
    if (t < NBLK) blk_off[t] = sc[t] - v;  // exclusive
}

__global__ void k_scan_c(const int* __restrict__ deg_out, const int* __restrict__ blk_off,
                         int* __restrict__ row_start, int* __restrict__ cursor) {
    __shared__ int sc[256];
    int t = threadIdx.x;
    int g = blockIdx.x * 256 + t;
    int v = (g < N_NODES) ? deg_out[g] : 0;
    sc[t] = v;
    __syncthreads();
    for (int off = 1; off < 256; off <<= 1) {
        int a = (t >= off) ? sc[t - off] : 0;
        __syncthreads();
        sc[t] += a;
        __syncthreads();
    }
    if (g < N_NODES) {
        int rs = blk_off[blockIdx.x] + sc[t] - v;
        row_start[g] = rs;
        cursor[g] = rs;
    }
}

// ---- bucket edges by destination (sources only; weights are separable) ----
__global__ void k_fill(const int2* __restrict__ el2, int* __restrict__ cursor,
                       int* __restrict__ srcs) {
    int e = blockIdx.x * blockDim.x + threadIdx.x;
    if (e < N_EDGES) {
        int2 st = el2[e];
        srcs[atomicAdd(&cursor[st.y], 1)] = st.x;
    }
}

// ---- xs[n] = bf16(rsqrt(deg_in[n]+1) * x[n]) : prescaled source features ----
__global__ void k_prescale(const float4* __restrict__ x4, const int* __restrict__ deg_in,
                           uint4* __restrict__ xs16) {
    int g = blockIdx.x * blockDim.x + threadIdx.x;  // N*16 groups of 8 elems
    int n = g >> 4;
    float rs = rsqrtf((float)(deg_in[n] + 1));
    float4 a = x4[g * 2], c = x4[g * 2 + 1];
    uint4 o;
    o.x = f2bf(rs * a.x) | ((unsigned)f2bf(rs * a.y) << 16);
    o.y = f2bf(rs * a.z) | ((unsigned)f2bf(rs * a.w) << 16);
    o.z = f2bf(rs * c.x) | ((unsigned)f2bf(rs * c.y) << 16);
    o.w = f2bf(rs * c.z) | ((unsigned)f2bf(rs * c.w) << 16);
    xs16[g] = o;
}

// ---- gather: u[n] = bf16( rd[n] * (sum_{s in N(n)} xs[s] + xs[n]) ) ----
// 32 lanes/node, ushort4 (8B) per lane, edge loop unrolled x4.
__global__ __launch_bounds__(256) void k_gather(const unsigned short* __restrict__ xs,
                                                const int* __restrict__ srcs,
                                                const int* __restrict__ row_start,
                                                const int* __restrict__ deg_out,
                                                unsigned short* __restrict__ u) {
    int n  = blockIdx.x * 8 + (threadIdx.x >> 5);  // 6250*8 = 50000 exact
    int d4 = threadIdx.x & 31;
    int cnt = deg_out[n];
    float rd = rsqrtf((float)(cnt + 1));
    ushort4 sv = *(const ushort4*)&xs[n * D + d4 * 4];  // self (already rs-scaled)
    float a0 = bf2f(sv.x), a1 = bf2f(sv.y), a2 = bf2f(sv.z), a3 = bf2f(sv.w);
    const int* p = srcs + row_start[n];
    int k = 0;
    for (; k + 4 <= cnt; k += 4) {
        int s0 = p[k], s1 = p[k + 1], s2 = p[k + 2], s3 = p[k + 3];
        ushort4 v0 = *(const ushort4*)&xs[s0 * D + d4 * 4];
        ushort4 v1 = *(const ushort4*)&xs[s1 * D + d4 * 4];
        ushort4 v2 = *(const ushort4*)&xs[s2 * D + d4 * 4];
        ushort4 v3 = *(const ushort4*)&xs[s3 * D + d4 * 4];
        a0 += bf2f(v0.x); a1 += bf2f(v0.y); a2 += bf2f(v0.z); a3 += bf2f(v0.w);
        a0 += bf2f(v1.x); a1 += bf2f(v1.y); a2 += bf2f(v1.z); a3 += bf2f(v1.w);
        a0 += bf2f(v2.x); a1 += bf2f(v2.y); a2 += bf2f(v2.z); a3 += bf2f(v2.w);
        a0 += bf2f(v3.x); a1 += bf2f(v3.y); a2 += bf2f(v3.z); a3 += bf2f(v3.w);
    }
    for (; k < cnt; ++k) {
        ushort4 vv = *(const ushort4*)&xs[p[k] * D + d4 * 4];
        a0 += bf2f(vv.x); a1 += bf2f(vv.y); a2 += bf2f(vv.z); a3 += bf2f(vv.w);
    }
    ushort4 o;
    o.x = f2bf(rd * a0); o.y = f2bf(rd * a1); o.z = f2bf(rd * a2); o.w = f2bf(rd * a3);
    *(ushort4*)&u[n * D + d4 * 4] = o;
}

// ---- combine: out = relu(u @ W^T + b) via bf16 MFMA; grid-strided chunks ----
// A layout: A[m=lane&15][k=quad*8+j]; B[k][n=lane&15] = W[n][k]; C/D col=lane&15,
// row=quad*4+reg (verified by R2/R3 pass).
__global__ __launch_bounds__(256) void k_gemm(const float* __restrict__ W,
                                              const float* __restrict__ bias,
                                              const unsigned short* __restrict__ u,
                                              float* __restrict__ out) {
    __shared__ unsigned short Wl[128 * 136];
    const int tid = threadIdx.x;
    for (int i = tid; i < 128 * 32; i += 256) {
        int r = i >> 5, c = i & 31;
        float4 w4 = *(const float4*)&W[r * D + c * 4];
        ushort4 hh;
        hh.x = f2bf(w4.x); hh.y = f2bf(w4.y); hh.z = f2bf(w4.z); hh.w = f2bf(w4.w);
        *(ushort4*)&Wl[r * 136 + c * 4] = hh;
    }
    __syncthreads();

    const int wv = tid >> 6, lane = tid & 63, ml = lane & 15, q = lane >> 4;
    const int nchunks = (N_NODES + 63) / 64;

    for (int chunk = blockIdx.x; chunk < nchunks; chunk += gridDim.x) {
        int base = chunk * 64;
        int arow = base + wv * 16 + ml;

        short8 a[4];
        if (arow < N_NODES) {
            #pragma unroll
            for (int kt = 0; kt < 4; ++kt)
                a[kt] = *(const short8*)&u[arow * D + kt * 32 + q * 8];
        } else {
            #pragma unroll
            for (int kt = 0; kt < 4; ++kt) a[kt] = (short8){0, 0, 0, 0, 0, 0, 0, 0};
        }

        f32x4 acc[8];
        #pragma unroll
        for (int jj = 0; jj < 8; ++jj) acc[jj] = (f32x4){0.f, 0.f, 0.f, 0.f};

        #pragma unroll
        for (int jj = 0; jj < 8; ++jj) {
            #pragma unroll
            for (int kt = 0; kt < 4; ++kt) {
                short8 bw = *(const short8*)&Wl[(jj * 16 + ml) * 136 + kt * 32 + q * 8];
                acc[jj] = __builtin_amdgcn_mfma_f32_16x16x32_bf16(a[kt], bw, acc[jj], 0, 0, 0);
            }
        }

        #pragma unroll
        for (int jj = 0; jj < 8; ++jj) {
            float bj = bias[jj * 16 + ml];
            #pragma unroll
            for (int r4 = 0; r4 < 4; ++r4) {
                int node = base + wv * 16 + q * 4 + r4;
                if (node < N_NODES) {
                    float v = acc[jj][r4] + bj;
                    out[node * D + jj * 16 + ml] = v > 0.f ? v : 0.f;
                }
            }
        }
    }
}

extern "C" void kernel_launch(void* const* d_in, const int* in_sizes, int n_in,
                              void* d_out, int out_size, void* d_ws, size_t ws_size,
                              hipStream_t stream) {
    const int*   el = (const int*)d_in[0];
    const float* x  = (const float*)d_in[1];
    const float* W  = (const float*)d_in[2];
    const float* b  = (const float*)d_in[3];
    float* out = (float*)d_out;

    // workspace layout (4B words); every word below is fully written each call
    unsigned int* partials = (unsigned int*)d_ws;              // HP*NW  = 3.20M
    unsigned short* xs     = (unsigned short*)(partials + (size_t)HP * NW);  // N*128 u16 = 3.20M words
    unsigned short* u16b   = xs + (size_t)N_NODES * D;         // N*128 u16 = 3.20M words
    int* srcs      = (int*)(u16b + (size_t)N_NODES * D);       // E      = 0.80M
    int* deg_in    = srcs + N_EDGES;                           // N
    int* deg_out   = deg_in + N_NODES;                         // N
    int* cursor    = deg_out + N_NODES;                        // N
    int* row_start = cursor + N_NODES;                         // N
    int* blk_sum   = row_start + N_NODES;                      // 256
    int* blk_off   = blk_sum + 256;                            // 256
    // total ~ 10.6M words ~ 42.5 MB

    k_hist<<<HP, 256, 0, stream>>>((const int2*)el, partials);
    k_reduce<<<(NW + 255) / 256, 256, 0, stream>>>(partials, deg_in, deg_out);
    k_scan_a<<<NBLK, 256, 0, stream>>>(deg_out, blk_sum);
    k_scan_b<<<1, 256, 0, stream>>>(blk_sum, blk_off);
    k_scan_c<<<NBLK, 256, 0, stream>>>(deg_out, blk_off, row_start, cursor);
    k_prescale<<<N_NODES * 16 / 256, 256, 0, stream>>>((const float4*)x, deg_in, (uint4*)xs);
    k_fill<<<N_EDGES / 256, 256, 0, stream>>>((const int2*)el, cursor, srcs);
    k_gather<<<N_NODES / 8, 256, 0, stream>>>(xs, srcs, row_start, deg_out, u16b);
    k_gemm<<<256, 256, 0, stream>>>(W, b, u16b, out);
}

// Round 5
// 195.412 us; speedup vs baseline: 3.1301x; 1.0443x over previous
//
#include <hip/hip_runtime.h>

#define N_NODES 50000
#define N_EDGES 800000
#define D 128
#define NBLK 196            // ceil(50000/256) for scans
#define HP 128              // histogram / fill partition blocks
#define EPB (N_EDGES / HP)  // 6250 edges per partition
#define NW (N_NODES / 2)    // 25000 packed u32 words (2 nodes/word)

typedef __attribute__((ext_vector_type(8))) short short8;   // 8 bf16
typedef __attribute__((ext_vector_type(4))) float f32x4;

__device__ __forceinline__ unsigned short f2bf(float f) {
    unsigned u = __float_as_uint(f);
    return (unsigned short)((u + 0x7FFFu + ((u >> 16) & 1u)) >> 16);  // RNE
}
__device__ __forceinline__ float bf2f(unsigned short h) {
    return __uint_as_float((unsigned)h << 16);
}

// ---- degrees via per-block LDS histograms (no global atomics) ----
// LDS word w packs: in[2w](b0) | out[2w](b1) | in[2w+1](b2) | out[2w+1](b3), u8 each.
__global__ __launch_bounds__(256) void k_hist(const int2* __restrict__ el2,
                                              unsigned int* __restrict__ partials) {
    __shared__ unsigned int h[NW];  // 100 KB
    int t = threadIdx.x;
    for (int i = t; i < NW / 4; i += 256) ((uint4*)h)[i] = make_uint4(0, 0, 0, 0);
    __syncthreads();
    const int2* p = el2 + blockIdx.x * EPB;
    for (int i = t; i < EPB; i += 256) {
        int2 st = p[i];
        atomicAdd(&h[st.x >> 1], 1u << ((st.x & 1) * 16));       // in-degree byte
        atomicAdd(&h[st.y >> 1], 256u << ((st.y & 1) * 16));     // out-degree byte
    }
    __syncthreads();
    uint4* dst = (uint4*)(partials + (size_t)blockIdx.x * NW);
    for (int i = t; i < NW / 4; i += 256) dst[i] = ((uint4*)h)[i];
}

// sum the HP partials with packed-u16 masked adds (128*255 < 65536: no carry)
__global__ void k_reduce(const unsigned int* __restrict__ partials,
                         int* __restrict__ deg_in, int* __restrict__ deg_out) {
    int w = blockIdx.x * blockDim.x + threadIdx.x;
    if (w >= NW) return;
    unsigned int si = 0, so = 0;
    for (int p = 0; p < HP; ++p) {
        unsigned int v = partials[p * NW + w];
        si += v & 0x00FF00FFu;
        so += (v >> 8) & 0x00FF00FFu;
    }
    *(int2*)&deg_in[2 * w]  = make_int2(si & 0xFFFF, si >> 16);
    *(int2*)&deg_out[2 * w] = make_int2(so & 0xFFFF, so >> 16);
}

// ---- scans over deg_out -> row_start ----
__global__ void k_scan_a(const int* __restrict__ deg_out, int* __restrict__ blk_sum) {
    __shared__ int sc[256];
    int t = threadIdx.x;
    int g = blockIdx.x * 256 + t;
    sc[t] = (g < N_NODES) ? deg_out[g] : 0;
    __syncthreads();
    for (int s = 128; s > 0; s >>= 1) {
        if (t < s) sc[t] += sc[t + s];
        __syncthreads();
    }
    if (t == 0) blk_sum[blockIdx.x] = sc[0];
}

__global__ void k_scan_b(const int* __restrict__ blk_sum, int* __restrict__ blk_off) {
    __shared__ int sc[256];
    int t = threadIdx.x;
    int v = (t < NBLK) ? blk_sum[t] : 0;
    sc[t] = v;
    __syncthreads();
    for (int off = 1; off < 256; off <<= 1) {
        int a = (t >= off) ? sc[t - off] : 0;
        __syncthreads();
        sc[t] += a;
        __syncthreads();
    }
    if (t < NBLK) blk_off[t] = sc[t] - v;  // exclusive
}

__global__ void k_scan_c(const int* __restrict__ deg_out, const int* __restrict__ blk_off,
                         int* __restrict__ row_start) {
    __shared__ int sc[256];
    int t = threadIdx.x;
    int g = blockIdx.x * 256 + t;
    int v = (g < N_NODES) ? deg_out[g] : 0;
    sc[t] = v;
    __syncthreads();
    for (int off = 1; off < 256; off <<= 1) {
        int a = (t >= off) ? sc[t - off] : 0;
        __syncthreads();
        sc[t] += a;
        __syncthreads();
    }
    if (g < N_NODES) row_start[g] = blk_off[blockIdx.x] + sc[t] - v;
}

// ---- per-(block,node) exclusive prefix of out-counts across blocks, u8 ----
// thread t owns nodes 4t..4t+3; for each p: write prefix bytes, then accumulate.
__global__ void k_colscan(const unsigned int* __restrict__ partials,
                          unsigned char* __restrict__ brel) {
    int t = blockIdx.x * blockDim.x + threadIdx.x;
    if (t >= N_NODES / 4) return;
    unsigned r0 = 0, r1 = 0, r2 = 0, r3 = 0;
    for (int p = 0; p < HP; ++p) {
        ((unsigned int*)brel)[p * (N_NODES / 4) + t] =
            r0 | (r1 << 8) | (r2 << 16) | (r3 << 24);
        unsigned v0 = partials[p * NW + 2 * t];
        unsigned v1 = partials[p * NW + 2 * t + 1];
        r0 += (v0 >> 8) & 0xFF;  r1 += (v0 >> 24) & 0xFF;
        r2 += (v1 >> 8) & 0xFF;  r3 += (v1 >> 24) & 0xFF;
    }
}

// ---- counting-sort placement, NO global atomics ----
// local rank via packed-u16 LDS cursors; pos = row_start + cross-block prefix + rank.
__global__ __launch_bounds__(256) void k_fill(const int2* __restrict__ el2,
                                              const int* __restrict__ row_start,
                                              const unsigned char* __restrict__ brel,
                                              int* __restrict__ srcs) {
    __shared__ unsigned int cur[NW];  // 100 KB packed u16 cursors
    int t = threadIdx.x;
    for (int i = t; i < NW / 4; i += 256) ((uint4*)cur)[i] = make_uint4(0, 0, 0, 0);
    __syncthreads();
    const int2* p = el2 + blockIdx.x * EPB;
    const unsigned char* br = brel + (size_t)blockIdx.x * N_NODES;
    for (int i = t; i < EPB; i += 256) {
        int2 st = p[i];
        int n = st.y;
        unsigned old = atomicAdd(&cur[n >> 1], 1u << ((n & 1) * 16));
        int rank = (old >> ((n & 1) * 16)) & 0xFFFF;
        srcs[row_start[n] + (int)br[n] + rank] = st.x;
    }
}

// ---- xs[n] = bf16(rsqrt(deg_in[n]+1) * x[n]) ----
__global__ void k_prescale(const float4* __restrict__ x4, const int* __restrict__ deg_in,
                           uint4* __restrict__ xs16) {
    int g = blockIdx.x * blockDim.x + threadIdx.x;  // N*16 groups of 8 elems
    int n = g >> 4;
    float rs = rsqrtf((float)(deg_in[n] + 1));
    float4 a = x4[g * 2], c = x4[g * 2 + 1];
    uint4 o;
    o.x = f2bf(rs * a.x) | ((unsigned)f2bf(rs * a.y) << 16);
    o.y = f2bf(rs * a.z) | ((unsigned)f2bf(rs * a.w) << 16);
    o.z = f2bf(rs * c.x) | ((unsigned)f2bf(rs * c.y) << 16);
    o.w = f2bf(rs * c.z) | ((unsigned)f2bf(rs * c.w) << 16);
    xs16[g] = o;
}

// ---- gather: u[n] = bf16( rd[n] * (sum_{s in N(n)} xs[s] + xs[n]) ) ----
// 32 lanes/node, ushort4 (8B)/lane, unrolled x8 for outstanding L3 gathers.
__global__ __launch_bounds__(256) void k_gather(const unsigned short* __restrict__ xs,
                                                const int* __restrict__ srcs,
                                                const int* __restrict__ row_start,
                                                const int* __restrict__ deg_out,
                                                unsigned short* __restrict__ u) {
    int n  = blockIdx.x * 8 + (threadIdx.x >> 5);  // 6250*8 = 50000 exact
    int d4 = threadIdx.x & 31;
    int cnt = deg_out[n];
    float rd = rsqrtf((float)(cnt + 1));
    ushort4 sv = *(const ushort4*)&xs[n * D + d4 * 4];  // self (rs-scaled)
    float a0 = bf2f(sv.x), a1 = bf2f(sv.y), a2 = bf2f(sv.z), a3 = bf2f(sv.w);
    const int* p = srcs + row_start[n];
    int k = 0;
    for (; k + 8 <= cnt; k += 8) {
        ushort4 v[8];
        #pragma unroll
        for (int j = 0; j < 8; ++j)
            v[j] = *(const ushort4*)&xs[p[k + j] * D + d4 * 4];
        #pragma unroll
        for (int j = 0; j < 8; ++j) {
            a0 += bf2f(v[j].x); a1 += bf2f(v[j].y);
            a2 += bf2f(v[j].z); a3 += bf2f(v[j].w);
        }
    }
    for (; k + 4 <= cnt; k += 4) {
        ushort4 v[4];
        #pragma unroll
        for (int j = 0; j < 4; ++j)
            v[j] = *(const ushort4*)&xs[p[k + j] * D + d4 * 4];
        #pragma unroll
        for (int j = 0; j < 4; ++j) {
            a0 += bf2f(v[j].x); a1 += bf2f(v[j].y);
            a2 += bf2f(v[j].z); a3 += bf2f(v[j].w);
        }
    }
    for (; k < cnt; ++k) {
        ushort4 vv = *(const ushort4*)&xs[p[k] * D + d4 * 4];
        a0 += bf2f(vv.x); a1 += bf2f(vv.y); a2 += bf2f(vv.z); a3 += bf2f(vv.w);
    }
    ushort4 o;
    o.x = f2bf(rd * a0); o.y = f2bf(rd * a1); o.z = f2bf(rd * a2); o.w = f2bf(rd * a3);
    *(ushort4*)&u[n * D + d4 * 4] = o;
}

// ---- combine: out = relu(u @ W^T + b) via bf16 MFMA; grid-strided ----
__global__ __launch_bounds__(256) void k_gemm(const float* __restrict__ W,
                                              const float* __restrict__ bias,
                                              const unsigned short* __restrict__ u,
                                              float* __restrict__ out) {
    __shared__ unsigned short Wl[128 * 136];
    const int tid = threadIdx.x;
    for (int i = tid; i < 128 * 32; i += 256) {
        int r = i >> 5, c = i & 31;
        float4 w4 = *(const float4*)&W[r * D + c * 4];
        ushort4 hh;
        hh.x = f2bf(w4.x); hh.y = f2bf(w4.y); hh.z = f2bf(w4.z); hh.w = f2bf(w4.w);
        *(ushort4*)&Wl[r * 136 + c * 4] = hh;
    }
    __syncthreads();

    const int wv = tid >> 6, lane = tid & 63, ml = lane & 15, q = lane >> 4;
    const int nchunks = (N_NODES + 63) / 64;

    for (int chunk = blockIdx.x; chunk < nchunks; chunk += gridDim.x) {
        int base = chunk * 64;
        int arow = base + wv * 16 + ml;

        short8 a[4];
        if (arow < N_NODES) {
            #pragma unroll
            for (int kt = 0; kt < 4; ++kt)
                a[kt] = *(const short8*)&u[arow * D + kt * 32 + q * 8];
        } else {
            #pragma unroll
            for (int kt = 0; kt < 4; ++kt) a[kt] = (short8){0, 0, 0, 0, 0, 0, 0, 0};
        }

        f32x4 acc[8];
        #pragma unroll
        for (int jj = 0; jj < 8; ++jj) acc[jj] = (f32x4){0.f, 0.f, 0.f, 0.f};

        #pragma unroll
        for (int jj = 0; jj < 8; ++jj) {
            #pragma unroll
            for (int kt = 0; kt < 4; ++kt) {
                short8 bw = *(const short8*)&Wl[(jj * 16 + ml) * 136 + kt * 32 + q * 8];
                acc[jj] = __builtin_amdgcn_mfma_f32_16x16x32_bf16(a[kt], bw, acc[jj], 0, 0, 0);
            }
        }

        #pragma unroll
        for (int jj = 0; jj < 8; ++jj) {
            float bj = bias[jj * 16 + ml];
            #pragma unroll
            for (int r4 = 0; r4 < 4; ++r4) {
                int node = base + wv * 16 + q * 4 + r4;
                if (node < N_NODES) {
                    float v = acc[jj][r4] + bj;
                    out[node * D + jj * 16 + ml] = v > 0.f ? v : 0.f;
                }
            }
        }
    }
}

extern "C" void kernel_launch(void* const* d_in, const int* in_sizes, int n_in,
                              void* d_out, int out_size, void* d_ws, size_t ws_size,
                              hipStream_t stream) {
    const int*   el = (const int*)d_in[0];
    const float* x  = (const float*)d_in[1];
    const float* W  = (const float*)d_in[2];
    const float* b  = (const float*)d_in[3];
    float* out = (float*)d_out;

    // workspace layout (4B words); brel aliases u16b (disjoint lifetimes:
    // brel written by colscan, read by fill; u16b written by gather AFTER fill).
    unsigned int* partials = (unsigned int*)d_ws;                       // HP*NW = 3.2M
    unsigned short* xs     = (unsigned short*)(partials + (size_t)HP * NW); // 3.2M words
    unsigned short* u16b   = xs + (size_t)N_NODES * D;                  // 3.2M words
    unsigned char* brel    = (unsigned char*)u16b;                      // HP*N u8 = 1.6M words (alias)
    int* srcs      = (int*)(u16b + (size_t)N_NODES * D);                // E = 0.8M
    int* deg_in    = srcs + N_EDGES;                                    // N
    int* deg_out   = deg_in + N_NODES;                                  // N
    int* row_start = deg_out + N_NODES;                                 // N
    int* blk_sum   = row_start + N_NODES;                               // 256
    int* blk_off   = blk_sum + 256;                                     // 256
    // total ~10.6M words ~ 42.3 MB

    k_hist<<<HP, 256, 0, stream>>>((const int2*)el, partials);
    k_reduce<<<(NW + 255) / 256, 256, 0, stream>>>(partials, deg_in, deg_out);
    k_scan_a<<<NBLK, 256, 0, stream>>>(deg_out, blk_sum);
    k_scan_b<<<1, 256, 0, stream>>>(blk_sum, blk_off);
    k_scan_c<<<NBLK, 256, 0, stream>>>(deg_out, blk_off, row_start);
    k_colscan<<<(N_NODES / 4 + 255) / 256, 256, 0, stream>>>(partials, brel);
    k_prescale<<<N_NODES * 16 / 256, 256, 0, stream>>>((const float4*)x, deg_in, (uint4*)xs);
    k_fill<<<HP, 256, 0, stream>>>((const int2*)el, row_start, brel, srcs);
    k_gather<<<N_NODES / 8, 256, 0, stream>>>(xs, srcs, row_start, deg_out, u16b);
    k_gemm<<<256, 256, 0, stream>>>(W, b, u16b, out);
}

// Round 7
// 190.938 us; speedup vs baseline: 3.2034x; 1.0234x over previous
//
#include <hip/hip_runtime.h>

#define N_NODES 50000
#define N_EDGES 800000
#define D 128
#define HP 128              // histogram / fill partition blocks
#define EPB (N_EDGES / HP)  // 6250 edges per partition
#define NW (N_NODES / 2)    // 25000 packed u32 words (2 nodes/word)
#define NWB 98              // ceil(NW/256) reduce/scan blocks (512 nodes each)
#define GNB 1563            // ceil(N_NODES/32) gather blocks per feature pass

typedef __attribute__((ext_vector_type(8))) short short8;   // 8 bf16
typedef __attribute__((ext_vector_type(4))) float f32x4;

__device__ __forceinline__ unsigned short f2bf(float f) {
    unsigned u = __float_as_uint(f);
    return (unsigned short)((u + 0x7FFFu + ((u >> 16) & 1u)) >> 16);  // RNE
}
__device__ __forceinline__ float bf2f(unsigned short h) {
    return __uint_as_float((unsigned)h << 16);
}

// ---- degrees via per-block LDS histograms (no global atomics) ----
// LDS word w packs: in[2w](b0) | out[2w](b1) | in[2w+1](b2) | out[2w+1](b3), u8 each.
__global__ __launch_bounds__(256) void k_hist(const int2* __restrict__ el2,
                                              unsigned int* __restrict__ partials) {
    __shared__ unsigned int h[NW];  // 100 KB
    int t = threadIdx.x;
    for (int i = t; i < NW / 4; i += 256) ((uint4*)h)[i] = make_uint4(0, 0, 0, 0);
    __syncthreads();
    const int2* p = el2 + blockIdx.x * EPB;
    for (int i = t; i < EPB; i += 256) {
        int2 st = p[i];
        atomicAdd(&h[st.x >> 1], 1u << ((st.x & 1) * 16));       // in-degree byte
        atomicAdd(&h[st.y >> 1], 256u << ((st.y & 1) * 16));     // out-degree byte
    }
    __syncthreads();
    uint4* dst = (uint4*)(partials + (size_t)blockIdx.x * NW);
    for (int i = t; i < NW / 4; i += 256) dst[i] = ((uint4*)h)[i];
}

// ---- fused: degree totals + cross-block exclusive prefixes (brel) + 512-node
// block sums for the row_start scan. One pass over `partials`.
// NOTE: so = sum of (v>>8)&0x00FF00FF, so out[2w] is in so[15:0] and
// out[2w+1] in so[31:16] (counts <= ~60, high bytes stay 0). R5's bug was
// extracting (so>>8)&0xFF / (so>>24)&0xFF — the always-zero high bytes. ----
__global__ __launch_bounds__(256) void k_reduce(const unsigned int* __restrict__ partials,
                                                unsigned char* __restrict__ brel,
                                                int* __restrict__ deg_in,
                                                int* __restrict__ deg_out,
                                                int* __restrict__ blk_sum) {
    __shared__ int sc[256];
    int t = threadIdx.x;
    int w = blockIdx.x * 256 + t;
    unsigned int si = 0, so = 0;
    if (w < NW) {
        for (int p = 0; p < HP; ++p) {
            // exclusive prefix of out-counts for (block p, nodes 2w, 2w+1), u8 each
            unsigned pre = (so & 0xFFu) | (((so >> 16) & 0xFFu) << 8);
            ((unsigned short*)(brel + (size_t)p * N_NODES))[w] = (unsigned short)pre;
            unsigned int v = partials[p * NW + w];
            si += v & 0x00FF00FFu;
            so += (v >> 8) & 0x00FF00FFu;
        }
        *(int2*)&deg_in[2 * w]  = make_int2(si & 0xFFFF, si >> 16);
        *(int2*)&deg_out[2 * w] = make_int2(so & 0xFFFF, so >> 16);
    }
    sc[t] = (w < NW) ? (int)((so & 0xFFFFu) + (so >> 16)) : 0;
    __syncthreads();
    for (int s = 128; s > 0; s >>= 1) {
        if (t < s) sc[t] += sc[t + s];
        __syncthreads();
    }
    if (t == 0) blk_sum[blockIdx.x] = sc[0];
}

// exclusive scan of the NWB block sums (single block)
__global__ void k_scan_b(const int* __restrict__ blk_sum, int* __restrict__ blk_off) {
    __shared__ int sc[256];
    int t = threadIdx.x;
    int v = (t < NWB) ? blk_sum[t] : 0;
    sc[t] = v;
    __syncthreads();
    for (int off = 1; off < 256; off <<= 1) {
        int a = (t >= off) ? sc[t - off] : 0;
        __syncthreads();
        sc[t] += a;
        __syncthreads();
    }
    if (t < NWB) blk_off[t] = sc[t] - v;  // exclusive
}

// row_start over 512 nodes/block (2 per thread)
__global__ void k_scan_c(const int* __restrict__ deg_out, const int* __restrict__ blk_off,
                         int* __restrict__ row_start) {
    __shared__ int sc[256];
    int t = threadIdx.x;
    int w = blockIdx.x * 256 + t;
    int v0 = 0, v1 = 0;
    if (w < NW) { int2 d2 = *(const int2*)&deg_out[2 * w]; v0 = d2.x; v1 = d2.y; }
    int pair = v0 + v1;
    sc[t] = pair;
    __syncthreads();
    for (int off = 1; off < 256; off <<= 1) {
        int a = (t >= off) ? sc[t - off] : 0;
        __syncthreads();
        sc[t] += a;
        __syncthreads();
    }
    if (w < NW) {
        int base = blk_off[blockIdx.x] + sc[t] - pair;
        *(int2*)&row_start[2 * w] = make_int2(base, base + v0);
    }
}

// ---- counting-sort placement, NO global atomics; srcs stored as u16 ----
__global__ __launch_bounds__(256) void k_fill(const int2* __restrict__ el2,
                                              const int* __restrict__ row_start,
                                              const unsigned char* __restrict__ brel,
                                              unsigned short* __restrict__ srcs) {
    __shared__ unsigned int cur[NW];  // 100 KB packed u16 cursors
    int t = threadIdx.x;
    for (int i = t; i < NW / 4; i += 256) ((uint4*)cur)[i] = make_uint4(0, 0, 0, 0);
    __syncthreads();
    const int2* p = el2 + blockIdx.x * EPB;
    const unsigned char* br = brel + (size_t)blockIdx.x * N_NODES;
    for (int i = t; i < EPB; i += 256) {
        int2 st = p[i];
        int n = st.y;
        unsigned old = atomicAdd(&cur[n >> 1], 1u << ((n & 1) * 16));
        int rank = (old >> ((n & 1) * 16)) & 0xFFFF;
        srcs[row_start[n] + (int)br[n] + rank] = (unsigned short)st.x;
    }
}

// ---- xst[f][n][32] = bf16(rsqrt(deg_in[n]+1) * x[n][f*32..f*32+32]) ----
__global__ void k_prescale(const float4* __restrict__ x4, const int* __restrict__ deg_in,
                           uint4* __restrict__ xst) {
    int g = blockIdx.x * blockDim.x + threadIdx.x;  // N*16 groups of 8 elems
    int n = g >> 4, part = g & 15;
    int f = part >> 2, off = part & 3;
    float rs = rsqrtf((float)(deg_in[n] + 1));
    float4 a = x4[g * 2], c = x4[g * 2 + 1];
    uint4 o;
    o.x = f2bf(rs * a.x) | ((unsigned)f2bf(rs * a.y) << 16);
    o.y = f2bf(rs * a.z) | ((unsigned)f2bf(rs * a.w) << 16);
    o.z = f2bf(rs * c.x) | ((unsigned)f2bf(rs * c.y) << 16);
    o.w = f2bf(rs * c.z) | ((unsigned)f2bf(rs * c.w) << 16);
    xst[(size_t)f * N_NODES * 4 + n * 4 + off] = o;  // uint4 units (8 bf16)
}

// ---- gather, feature-tiled: pass f reads only xst[f] (3.2MB, fits per-XCD L2) ----
// 8 lanes/node (ushort4 = 8B -> 64B/edge-chunk = 1 cacheline), unroll x8.
__global__ __launch_bounds__(256) void k_gather(const unsigned short* __restrict__ xst,
                                                const unsigned short* __restrict__ srcs,
                                                const int* __restrict__ row_start,
                                                const int* __restrict__ deg_out,
                                                unsigned short* __restrict__ ut) {
    int pass = blockIdx.x / GNB;       // pass-major: keeps one tile hot per window
    int idx  = blockIdx.x - pass * GNB;
    int n = idx * 32 + (threadIdx.x >> 3);
    if (n >= N_NODES) return;
    int d = threadIdx.x & 7;
    const unsigned short* xb = xst + (size_t)pass * N_NODES * 32;
    int cnt = deg_out[n];
    float rd = rsqrtf((float)(cnt + 1));
    ushort4 sv = *(const ushort4*)&xb[n * 32 + d * 4];  // self (rs-scaled)
    float a0 = bf2f(sv.x), a1 = bf2f(sv.y), a2 = bf2f(sv.z), a3 = bf2f(sv.w);
    const unsigned short* p = srcs + row_start[n];
    int k = 0;
    for (; k + 8 <= cnt; k += 8) {
        ushort4 v[8];
        #pragma unroll
        for (int j = 0; j < 8; ++j)
            v[j] = *(const ushort4*)&xb[(int)p[k + j] * 32 + d * 4];
        #pragma unroll
        for (int j = 0; j < 8; ++j) {
            a0 += bf2f(v[j].x); a1 += bf2f(v[j].y);
            a2 += bf2f(v[j].z); a3 += bf2f(v[j].w);
        }
    }
    for (; k < cnt; ++k) {
        ushort4 vv = *(const ushort4*)&xb[(int)p[k] * 32 + d * 4];
        a0 += bf2f(vv.x); a1 += bf2f(vv.y); a2 += bf2f(vv.z); a3 += bf2f(vv.w);
    }
    ushort4 o;
    o.x = f2bf(rd * a0); o.y = f2bf(rd * a1); o.z = f2bf(rd * a2); o.w = f2bf(rd * a3);
    *(ushort4*)&ut[(size_t)pass * N_NODES * 32 + n * 32 + d * 4] = o;
}

// ---- combine: out = relu(u @ W^T + b) via bf16 MFMA; u is feature-tiled ----
__global__ __launch_bounds__(256) void k_gemm(const float* __restrict__ W,
                                              const float* __restrict__ bias,
                                              const unsigned short* __restrict__ ut,
                                              float* __restrict__ out) {
    __shared__ unsigned short Wl[128 * 136];
    const int tid = threadIdx.x;
    for (int i = tid; i < 128 * 32; i += 256) {
        int r = i >> 5, c = i & 31;
        float4 w4 = *(const float4*)&W[r * D + c * 4];
        ushort4 hh;
        hh.x = f2bf(w4.x); hh.y = f2bf(w4.y); hh.z = f2bf(w4.z); hh.w = f2bf(w4.w);
        *(ushort4*)&Wl[r * 136 + c * 4] = hh;
    }
    __syncthreads();

    const int wv = tid >> 6, lane = tid & 63, ml = lane & 15, q = lane >> 4;
    const int nchunks = (N_NODES + 63) / 64;

    for (int chunk = blockIdx.x; chunk < nchunks; chunk += gridDim.x) {
        int base = chunk * 64;
        int arow = base + wv * 16 + ml;

        short8 a[4];
        if (arow < N_NODES) {
            #pragma unroll
            for (int kt = 0; kt < 4; ++kt)   // k-chunk kt lives in tile kt
                a[kt] = *(const short8*)&ut[(size_t)kt * N_NODES * 32 + arow * 32 + q * 8];
        } else {
            #pragma unroll
            for (int kt = 0; kt < 4; ++kt) a[kt] = (short8){0, 0, 0, 0, 0, 0, 0, 0};
        }

        f32x4 acc[8];
        #pragma unroll
        for (int jj = 0; jj < 8; ++jj) acc[jj] = (f32x4){0.f, 0.f, 0.f, 0.f};

        #pragma unroll
        for (int jj = 0; jj < 8; ++jj) {
            #pragma unroll
            for (int kt = 0; kt < 4; ++kt) {
                short8 bw = *(const short8*)&Wl[(jj * 16 + ml) * 136 + kt * 32 + q * 8];
                acc[jj] = __builtin_amdgcn_mfma_f32_16x16x32_bf16(a[kt], bw, acc[jj], 0, 0, 0);
            }
        }

        #pragma unroll
        for (int jj = 0; jj < 8; ++jj) {
            float bj = bias[jj * 16 + ml];
            #pragma unroll
            for (int r4 = 0; r4 < 4; ++r4) {
                int node = base + wv * 16 + q * 4 + r4;
                if (node < N_NODES) {
                    float v = acc[jj][r4] + bj;
                    out[node * D + jj * 16 + ml] = v > 0.f ? v : 0.f;
                }
            }
        }
    }
}

extern "C" void kernel_launch(void* const* d_in, const int* in_sizes, int n_in,
                              void* d_out, int out_size, void* d_ws, size_t ws_size,
                              hipStream_t stream) {
    const int*   el = (const int*)d_in[0];
    const float* x  = (const float*)d_in[1];
    const float* W  = (const float*)d_in[2];
    const float* b  = (const float*)d_in[3];
    float* out = (float*)d_out;

    // workspace layout (4B words); brel aliases ut (disjoint lifetimes:
    // brel written by k_reduce, read by k_fill; ut written by k_gather AFTER fill).
    unsigned int* partials = (unsigned int*)d_ws;                           // HP*NW = 3.2M
    unsigned short* xst    = (unsigned short*)(partials + (size_t)HP * NW); // N*128 bf16
    unsigned short* ut     = xst + (size_t)N_NODES * D;                     // N*128 bf16
    unsigned char* brel    = (unsigned char*)ut;                            // HP*N u8 (alias)
    unsigned short* srcs   = ut + (size_t)N_NODES * D;                      // E u16 = 0.4M words
    int* deg_in    = (int*)(srcs + N_EDGES);                                // N
    int* deg_out   = deg_in + N_NODES;                                      // N
    int* row_start = deg_out + N_NODES;                                     // N
    int* blk_sum   = row_start + N_NODES;                                   // 256
    int* blk_off   = blk_sum + 256;                                         // 256
    // total ~ 40 MB

    k_hist<<<HP, 256, 0, stream>>>((const int2*)el, partials);
    k_reduce<<<NWB, 256, 0, stream>>>(partials, brel, deg_in, deg_out, blk_sum);
    k_scan_b<<<1, 256, 0, stream>>>(blk_sum, blk_off);
    k_scan_c<<<NWB, 256, 0, stream>>>(deg_out, blk_off, row_start);
    k_prescale<<<N_NODES * 16 / 256, 256, 0, stream>>>((const float4*)x, deg_in, (uint4*)xst);
    k_fill<<<HP, 256, 0, stream>>>((const int2*)el, row_start, brel, srcs);
    k_gather<<<4 * GNB, 256, 0, stream>>>(xst, srcs, row_start, deg_out, ut);
    k_gemm<<<256, 256, 0, stream>>>(W, b, ut, out);
}